// Round 1
// baseline (4109.993 us; speedup 1.0000x reference)
//
#include <hip/hip_runtime.h>
#include <math.h>

#define HIDDEN 1024
#define HEADS 16
#define HEAD_DIM 64
#define EPS 1e-5f

// ---------------------------------------------------------------------------
// GEMM: C[M,N] = A[M,K] @ W[K,N] + bias[N]   (all row-major fp32)
// BM=BN=64, BK=16, 256 threads (16x16), each thread 4x4 outputs.
// ---------------------------------------------------------------------------
__global__ __launch_bounds__(256) void gemm_bias_kernel(
    const float* __restrict__ A, const float* __restrict__ W,
    const float* __restrict__ bias, float* __restrict__ C,
    int M, int N, int K)
{
    __shared__ float As[64][17];
    __shared__ float Bs[16][65];
    const int tid = threadIdx.x;
    const int tx = tid & 15;    // 0..15 col group
    const int ty = tid >> 4;    // 0..15 row group
    const int brow = blockIdx.y * 64;
    const int bcol = blockIdx.x * 64;

    float acc[4][4] = {};

    for (int k0 = 0; k0 < K; k0 += 16) {
        #pragma unroll
        for (int i = 0; i < 4; ++i) {
            int idx = tid + i * 256;          // 0..1023
            int r = idx >> 4, c = idx & 15;   // A tile 64x16
            As[r][c] = A[(size_t)(brow + r) * K + (k0 + c)];
        }
        #pragma unroll
        for (int i = 0; i < 4; ++i) {
            int idx = tid + i * 256;
            int r = idx >> 6, c = idx & 63;   // B tile 16x64
            Bs[r][c] = W[(size_t)(k0 + r) * N + (bcol + c)];
        }
        __syncthreads();
        #pragma unroll
        for (int kk = 0; kk < 16; ++kk) {
            float a[4], b[4];
            #pragma unroll
            for (int i = 0; i < 4; ++i) a[i] = As[ty * 4 + i][kk];
            #pragma unroll
            for (int j = 0; j < 4; ++j) b[j] = Bs[kk][tx * 4 + j];
            #pragma unroll
            for (int i = 0; i < 4; ++i)
                #pragma unroll
                for (int j = 0; j < 4; ++j)
                    acc[i][j] += a[i] * b[j];
        }
        __syncthreads();
    }

    #pragma unroll
    for (int i = 0; i < 4; ++i) {
        int r = brow + ty * 4 + i;
        #pragma unroll
        for (int j = 0; j < 4; ++j) {
            int c = bcol + tx * 4 + j;
            C[(size_t)r * N + c] = acc[i][j] + bias[c];
        }
    }
}

// ---------------------------------------------------------------------------
// Flash-style attention. Q/K/V laid out [B, S, HIDDEN] with head h at cols
// h*64..h*64+63. One block = (batch b, head h, 64 q-rows). 256 threads:
// thread t owns q-row (t>>2) and head-dim cols seg*16..seg*16+15 (seg=t&3).
// Online softmax over 32 k-tiles of 64.
// ---------------------------------------------------------------------------
__global__ __launch_bounds__(256) void attention_kernel(
    const float* __restrict__ Q, const float* __restrict__ K,
    const float* __restrict__ V, float* __restrict__ O, int S)
{
    const int qt = blockIdx.x;   // q tile
    const int h  = blockIdx.y;
    const int b  = blockIdx.z;
    const int tid = threadIdx.x;
    const int row = tid >> 2;    // 0..63
    const int seg = tid & 3;     // 0..3
    const float scale = 0.125f;  // 1/sqrt(64)

    __shared__ float Qs[64][HEAD_DIM + 1];
    __shared__ float Ks[64][HEAD_DIM + 1];
    __shared__ float Vs[64][HEAD_DIM + 1];
    __shared__ float Ps[64][64 + 1];
    __shared__ float red[64][4];

    const size_t base = ((size_t)b * S) * HIDDEN + (size_t)h * HEAD_DIM;

    #pragma unroll
    for (int i = 0; i < 16; ++i) {
        int idx = tid + i * 256;             // 0..4095
        int r = idx >> 6, d = idx & 63;
        Qs[r][d] = Q[base + (size_t)(qt * 64 + r) * HIDDEN + d];
    }

    float m = -3.402823466e38f, l = 0.f;
    float o[16] = {};
    __syncthreads();

    for (int kt = 0; kt < S / 64; ++kt) {
        #pragma unroll
        for (int i = 0; i < 16; ++i) {
            int idx = tid + i * 256;
            int r = idx >> 6, d = idx & 63;
            size_t g = base + (size_t)(kt * 64 + r) * HIDDEN + d;
            Ks[r][d] = K[g];
            Vs[r][d] = V[g];
        }
        __syncthreads();

        // scores for this thread's 16 k-columns
        float s[16];
        float mloc = -3.402823466e38f;
        #pragma unroll
        for (int j = 0; j < 16; ++j) {
            int kc = seg * 16 + j;
            float acc = 0.f;
            #pragma unroll
            for (int d = 0; d < 64; ++d) acc += Qs[row][d] * Ks[kc][d];
            s[j] = acc * scale;
            mloc = fmaxf(mloc, s[j]);
        }
        red[row][seg] = mloc;
        __syncthreads();
        float mtile = fmaxf(fmaxf(red[row][0], red[row][1]),
                            fmaxf(red[row][2], red[row][3]));
        float mnew = fmaxf(m, mtile);

        float lloc = 0.f;
        #pragma unroll
        for (int j = 0; j < 16; ++j) {
            float p = __expf(s[j] - mnew);
            Ps[row][seg * 16 + j] = p;
            lloc += p;
        }
        __syncthreads();            // Ps visible; red reads done
        red[row][seg] = lloc;
        __syncthreads();
        float ltile = red[row][0] + red[row][1] + red[row][2] + red[row][3];
        float alpha = __expf(m - mnew);
        l = l * alpha + ltile;
        m = mnew;

        // O[row][d] update for this thread's 16 d-columns
        #pragma unroll
        for (int j = 0; j < 16; ++j) {
            int d = seg * 16 + j;
            float acc = 0.f;
            #pragma unroll
            for (int kc = 0; kc < 64; ++kc) acc += Ps[row][kc] * Vs[kc][d];
            o[j] = o[j] * alpha + acc;
        }
        __syncthreads();            // before Ks/Vs/Ps overwrite
    }

    float inv_l = 1.f / l;
    #pragma unroll
    for (int j = 0; j < 16; ++j) {
        int d = seg * 16 + j;
        O[base + (size_t)(qt * 64 + row) * HIDDEN + d] = o[j] * inv_l;
    }
}

// ---------------------------------------------------------------------------
// out = LayerNorm(proj + residual) * gamma + beta, one block per row.
// ---------------------------------------------------------------------------
__global__ __launch_bounds__(256) void resln_kernel(
    const float* __restrict__ proj, const float* __restrict__ resid,
    const float* __restrict__ gamma, const float* __restrict__ beta,
    float* __restrict__ out)
{
    const int rowi = blockIdx.x;
    const float* p = proj + (size_t)rowi * HIDDEN;
    const float* r = resid + (size_t)rowi * HIDDEN;
    float* o = out + (size_t)rowi * HIDDEN;
    const int tid = threadIdx.x;

    __shared__ float xs[HIDDEN];
    __shared__ float red[8];

    float local = 0.f;
    for (int i = tid; i < HIDDEN; i += 256) {
        float x = p[i] + r[i];
        xs[i] = x;
        local += x;
    }
    const int wid = tid >> 6, lane = tid & 63;
    #pragma unroll
    for (int off = 32; off > 0; off >>= 1) local += __shfl_down(local, off, 64);
    if (lane == 0) red[wid] = local;
    __syncthreads();
    float mu = (red[0] + red[1] + red[2] + red[3]) * (1.f / HIDDEN);

    float lv = 0.f;
    for (int i = tid; i < HIDDEN; i += 256) {
        float d = xs[i] - mu;
        lv += d * d;
    }
    #pragma unroll
    for (int off = 32; off > 0; off >>= 1) lv += __shfl_down(lv, off, 64);
    if (lane == 0) red[4 + wid] = lv;
    __syncthreads();
    float var = (red[4] + red[5] + red[6] + red[7]) * (1.f / HIDDEN);
    float rstd = rsqrtf(var + EPS);

    for (int i = tid; i < HIDDEN; i += 256) {
        o[i] = (xs[i] - mu) * rstd * gamma[i] + beta[i];
    }
}

// ---------------------------------------------------------------------------
extern "C" void kernel_launch(void* const* d_in, const int* in_sizes, int n_in,
                              void* d_out, int out_size, void* d_ws, size_t ws_size,
                              hipStream_t stream)
{
    const float* X     = (const float*)d_in[0];
    const float* Wq    = (const float*)d_in[1];
    const float* bq    = (const float*)d_in[2];
    const float* Wk    = (const float*)d_in[3];
    const float* bk    = (const float*)d_in[4];
    const float* Wv    = (const float*)d_in[5];
    const float* bv    = (const float*)d_in[6];
    const float* Wo    = (const float*)d_in[7];
    const float* bo    = (const float*)d_in[8];
    const float* gamma = (const float*)d_in[9];
    const float* beta  = (const float*)d_in[10];
    float* out = (float*)d_out;

    const int B = 2, S = 2048;
    const int M = B * S;                 // 4096 rows
    const size_t mat = (size_t)M * HIDDEN;  // 4M elems = 16 MB fp32

    float* Qb = (float*)d_ws;
    float* Kb = Qb + mat;
    float* Vb = Kb + mat;
    float* Cb = Vb + mat;   // attention context
    float* Pb = Qb;         // output projection reuses Q slot

    dim3 blk(256);
    dim3 ggrid(HIDDEN / 64, M / 64);     // (16, 64)

    gemm_bias_kernel<<<ggrid, blk, 0, stream>>>(X, Wq, bq, Qb, M, HIDDEN, HIDDEN);
    gemm_bias_kernel<<<ggrid, blk, 0, stream>>>(X, Wk, bk, Kb, M, HIDDEN, HIDDEN);
    gemm_bias_kernel<<<ggrid, blk, 0, stream>>>(X, Wv, bv, Vb, M, HIDDEN, HIDDEN);

    dim3 agrid(S / 64, HEADS, B);        // (32, 16, 2)
    attention_kernel<<<agrid, blk, 0, stream>>>(Qb, Kb, Vb, Cb, S);

    gemm_bias_kernel<<<ggrid, blk, 0, stream>>>(Cb, Wo, bo, Pb, M, HIDDEN, HIDDEN);

    resln_kernel<<<M, blk, 0, stream>>>(Pb, X, gamma, beta, out);
}

// Round 2
// 366.288 us; speedup vs baseline: 11.2207x; 11.2207x over previous
//
#include <hip/hip_runtime.h>
#include <math.h>

#define HIDDEN 1024
#define HEADS 16
#define HEAD_DIM 64
#define EPS 1e-5f

typedef __attribute__((ext_vector_type(8))) short bf16x8;
typedef __attribute__((ext_vector_type(4))) float f32x4;

__device__ __forceinline__ short f2bf(float f) {
    union { float f; unsigned u; } v; v.f = f;
    unsigned r = v.u + 0x7fffu + ((v.u >> 16) & 1u);   // round-to-nearest-even
    return (short)(r >> 16);
}

// ---------------------------------------------------------------------------
// fp32 -> bf16 cast, 4 elems/thread
// ---------------------------------------------------------------------------
__global__ __launch_bounds__(256) void cast_bf16_kernel(
    const float* __restrict__ in, short* __restrict__ out, int n)
{
    int i = (blockIdx.x * 256 + threadIdx.x) * 4;
    if (i >= n) return;
    float4 v = *(const float4*)(in + i);
    short o[4] = { f2bf(v.x), f2bf(v.y), f2bf(v.z), f2bf(v.w) };
    *(uint2*)(out + i) = *(uint2*)o;
}

// ---------------------------------------------------------------------------
// W[K,N] fp32 -> Wt[N,K] bf16 (32x32 tiles through LDS)
// ---------------------------------------------------------------------------
__global__ __launch_bounds__(256) void transpose_cast_kernel(
    const float* __restrict__ W, short* __restrict__ Wt, int Kd, int Nd)
{
    __shared__ short tile[32][33];
    int n0 = blockIdx.x * 32;
    int k0 = blockIdx.y * 32;
    int tx = threadIdx.x & 31;
    int ty = threadIdx.x >> 5;  // 0..7
    #pragma unroll
    for (int i = 0; i < 32; i += 8)
        tile[ty + i][tx] = f2bf(W[(size_t)(k0 + ty + i) * Nd + n0 + tx]);
    __syncthreads();
    #pragma unroll
    for (int i = 0; i < 32; i += 8)
        Wt[(size_t)(n0 + ty + i) * Kd + k0 + tx] = tile[tx][ty + i];
}

// ---------------------------------------------------------------------------
// C[M,N] = A[M,K] @ Bt[N,K]^T + bias ; A,Bt bf16, out fp32 or bf16.
// 128x128 tile, BK=32, 256 threads = 4 waves, each wave a 64x64 quadrant
// of 4x4 16x16x32 MFMA tiles.
// ---------------------------------------------------------------------------
__global__ __launch_bounds__(256) void gemm_bt_mfma(
    const short* __restrict__ A, const short* __restrict__ Bt,
    const float* __restrict__ bias, void* __restrict__ C,
    int M, int N, int K, int out_bf16)
{
    __shared__ short As[128][40];   // pitch 40 shorts = 80 B (16B-aligned rows)
    __shared__ short Bs[128][40];
    const int tid = threadIdx.x;
    const int wave = tid >> 6, lane = tid & 63;
    const int ln16 = lane & 15, quad = lane >> 4;
    const int wm = (wave >> 1) * 64, wn = (wave & 1) * 64;
    const int brow = blockIdx.y * 128, bcol = blockIdx.x * 128;

    f32x4 acc[4][4];
    #pragma unroll
    for (int mt = 0; mt < 4; ++mt)
        #pragma unroll
        for (int nt = 0; nt < 4; ++nt) acc[mt][nt] = (f32x4){0.f, 0.f, 0.f, 0.f};

    for (int k0 = 0; k0 < K; k0 += 32) {
        #pragma unroll
        for (int i = 0; i < 2; ++i) {
            int idx = tid + i * 256;       // 0..511
            int r = idx >> 2;              // 0..127
            int c0 = (idx & 3) * 8;        // 0,8,16,24
            *(uint4*)&As[r][c0] = *(const uint4*)(A + (size_t)(brow + r) * K + k0 + c0);
            *(uint4*)&Bs[r][c0] = *(const uint4*)(Bt + (size_t)(bcol + r) * K + k0 + c0);
        }
        __syncthreads();
        bf16x8 af[4], bf[4];
        #pragma unroll
        for (int mt = 0; mt < 4; ++mt)
            af[mt] = *(const bf16x8*)&As[wm + mt * 16 + ln16][quad * 8];
        #pragma unroll
        for (int nt = 0; nt < 4; ++nt)
            bf[nt] = *(const bf16x8*)&Bs[wn + nt * 16 + ln16][quad * 8];
        #pragma unroll
        for (int mt = 0; mt < 4; ++mt)
            #pragma unroll
            for (int nt = 0; nt < 4; ++nt)
                acc[mt][nt] = __builtin_amdgcn_mfma_f32_16x16x32_bf16(
                    af[mt], bf[nt], acc[mt][nt], 0, 0, 0);
        __syncthreads();
    }

    // epilogue: C/D layout col=lane&15, row=quad*4+reg
    #pragma unroll
    for (int mt = 0; mt < 4; ++mt) {
        #pragma unroll
        for (int r = 0; r < 4; ++r) {
            int row = brow + wm + mt * 16 + quad * 4 + r;
            #pragma unroll
            for (int nt = 0; nt < 4; ++nt) {
                int col = bcol + wn + nt * 16 + ln16;
                float v = acc[mt][nt][r] + bias[col];
                if (out_bf16) ((short*)C)[(size_t)row * N + col] = f2bf(v);
                else          ((float*)C)[(size_t)row * N + col] = v;
            }
        }
    }
}

// ---------------------------------------------------------------------------
// MFMA flash attention. Q,K,V,Ctx bf16 [B,S,HIDDEN], head h at cols h*64..+63.
// Block = (b, h, 64 q-rows); 4 waves, wave w owns q-rows w*16..+15.
// ---------------------------------------------------------------------------
__device__ __forceinline__ int vt_off(int d, int kp) {
    // V^T in LDS, pitch 72 shorts; XOR-swizzle k' in blocks of 8 to avoid
    // 8-way bank conflicts on the transposed staging writes.
    int k8 = (kp >> 3) ^ ((d >> 3) & 7);
    return d * 72 + k8 * 8 + (kp & 7);
}
__device__ __forceinline__ int ps_off(int row, int kp) {
    int k8 = (kp >> 3) ^ ((row >> 1) & 7);
    return row * 72 + k8 * 8 + (kp & 7);
}

__global__ __launch_bounds__(256) void attn_mfma_kernel(
    const short* __restrict__ Qb, const short* __restrict__ Kb,
    const short* __restrict__ Vb, short* __restrict__ Ctx, int S)
{
    const int qt = blockIdx.x, h = blockIdx.y, b = blockIdx.z;
    const int tid = threadIdx.x;
    const int wave = tid >> 6, lane = tid & 63;
    const int ln16 = lane & 15, quad = lane >> 4;

    __shared__ short Qs[64][72];
    __shared__ short Ks[64][72];
    __shared__ short VtF[64 * 72];   // V^T, swizzled
    __shared__ short PsF[64 * 72];   // P,   swizzled

    const size_t base = ((size_t)b * S) * HIDDEN + (size_t)h * HEAD_DIM;

    // stage Q tile (64 rows x 64 d), 8 bf16 per thread-iter
    #pragma unroll
    for (int i = 0; i < 2; ++i) {
        int idx = tid + i * 256;             // 0..511
        int r = idx >> 3, d0 = (idx & 7) * 8;
        *(uint4*)&Qs[r][d0] =
            *(const uint4*)(Qb + base + (size_t)(qt * 64 + r) * HIDDEN + d0);
    }
    __syncthreads();

    bf16x8 qfrag[2];
    #pragma unroll
    for (int kb = 0; kb < 2; ++kb)
        qfrag[kb] = *(const bf16x8*)&Qs[wave * 16 + ln16][kb * 32 + quad * 8];

    float m_i[4], l_i[4];
    #pragma unroll
    for (int r = 0; r < 4; ++r) { m_i[r] = -1e30f; l_i[r] = 0.f; }
    f32x4 ofrag[4];
    #pragma unroll
    for (int nt = 0; nt < 4; ++nt) ofrag[nt] = (f32x4){0.f, 0.f, 0.f, 0.f};

    for (int kt = 0; kt < S / 64; ++kt) {
        __syncthreads();   // prev iter's Ps/Vt/Ks reads done before restage
        #pragma unroll
        for (int i = 0; i < 2; ++i) {
            int idx = tid + i * 256;
            int r = idx >> 3, d0 = (idx & 7) * 8;
            const short* kp = Kb + base + (size_t)(kt * 64 + r) * HIDDEN + d0;
            *(uint4*)&Ks[r][d0] = *(const uint4*)kp;
            uint4 vv = *(const uint4*)(Vb + base + (size_t)(kt * 64 + r) * HIDDEN + d0);
            const short* vs = (const short*)&vv;
            #pragma unroll
            for (int j = 0; j < 8; ++j) VtF[vt_off(d0 + j, r)] = vs[j];
        }
        __syncthreads();

        // S = (Q K^T) * 0.125 ; wave computes its 16 rows x 64 cols
        f32x4 sfrag[4];
        #pragma unroll
        for (int nt = 0; nt < 4; ++nt) {
            f32x4 a = (f32x4){0.f, 0.f, 0.f, 0.f};
            #pragma unroll
            for (int kb = 0; kb < 2; ++kb) {
                bf16x8 kf = *(const bf16x8*)&Ks[nt * 16 + ln16][kb * 32 + quad * 8];
                a = __builtin_amdgcn_mfma_f32_16x16x32_bf16(qfrag[kb], kf, a, 0, 0, 0);
            }
            #pragma unroll
            for (int r = 0; r < 4; ++r) a[r] *= 0.125f;
            sfrag[nt] = a;
        }

        // online softmax; row (= quad*4+r) cols live in this quad's 16 lanes
        float alpha[4];
        #pragma unroll
        for (int r = 0; r < 4; ++r) {
            float mx = fmaxf(fmaxf(sfrag[0][r], sfrag[1][r]),
                             fmaxf(sfrag[2][r], sfrag[3][r]));
            #pragma unroll
            for (int off = 1; off < 16; off <<= 1)
                mx = fmaxf(mx, __shfl_xor(mx, off, 64));
            float mnew = fmaxf(m_i[r], mx);
            alpha[r] = __expf(m_i[r] - mnew);
            m_i[r] = mnew;
        }
        float lsum[4] = {0.f, 0.f, 0.f, 0.f};
        #pragma unroll
        for (int nt = 0; nt < 4; ++nt) {
            #pragma unroll
            for (int r = 0; r < 4; ++r) {
                float p = __expf(sfrag[nt][r] - m_i[r]);
                lsum[r] += p;
                PsF[ps_off(wave * 16 + quad * 4 + r, nt * 16 + ln16)] = f2bf(p);
            }
        }
        #pragma unroll
        for (int r = 0; r < 4; ++r) {
            #pragma unroll
            for (int off = 1; off < 16; off <<= 1)
                lsum[r] += __shfl_xor(lsum[r], off, 64);
            l_i[r] = l_i[r] * alpha[r] + lsum[r];
        }
        #pragma unroll
        for (int nt = 0; nt < 4; ++nt)
            #pragma unroll
            for (int r = 0; r < 4; ++r) ofrag[nt][r] *= alpha[r];

        __syncthreads();   // P visible (cross-lane), Vt staged

        // O += P V : A = P rows (this wave's 16), B = V^T rows
        bf16x8 pf[2];
        #pragma unroll
        for (int kb = 0; kb < 2; ++kb)
            pf[kb] = *(const bf16x8*)&PsF[ps_off(wave * 16 + ln16, kb * 32 + quad * 8)];
        #pragma unroll
        for (int nt = 0; nt < 4; ++nt) {
            f32x4 a = ofrag[nt];
            #pragma unroll
            for (int kb = 0; kb < 2; ++kb) {
                bf16x8 vf = *(const bf16x8*)&VtF[vt_off(nt * 16 + ln16, kb * 32 + quad * 8)];
                a = __builtin_amdgcn_mfma_f32_16x16x32_bf16(pf[kb], vf, a, 0, 0, 0);
            }
            ofrag[nt] = a;
        }
    }

    #pragma unroll
    for (int r = 0; r < 4; ++r) {
        float inv = 1.f / l_i[r];
        int row = qt * 64 + wave * 16 + quad * 4 + r;
        #pragma unroll
        for (int nt = 0; nt < 4; ++nt) {
            Ctx[base + (size_t)row * HIDDEN + nt * 16 + ln16] =
                f2bf(ofrag[nt][r] * inv);
        }
    }
}

// ---------------------------------------------------------------------------
// out = LayerNorm(proj + residual) * gamma + beta, one block per row (fp32)
// ---------------------------------------------------------------------------
__global__ __launch_bounds__(256) void resln_kernel(
    const float* __restrict__ proj, const float* __restrict__ resid,
    const float* __restrict__ gamma, const float* __restrict__ beta,
    float* __restrict__ out)
{
    const int rowi = blockIdx.x;
    const float* p = proj + (size_t)rowi * HIDDEN;
    const float* r = resid + (size_t)rowi * HIDDEN;
    float* o = out + (size_t)rowi * HIDDEN;
    const int tid = threadIdx.x;

    __shared__ float xs[HIDDEN];
    __shared__ float red[8];

    float local = 0.f;
    for (int i = tid; i < HIDDEN; i += 256) {
        float x = p[i] + r[i];
        xs[i] = x;
        local += x;
    }
    const int wid = tid >> 6, lane = tid & 63;
    #pragma unroll
    for (int off = 32; off > 0; off >>= 1) local += __shfl_down(local, off, 64);
    if (lane == 0) red[wid] = local;
    __syncthreads();
    float mu = (red[0] + red[1] + red[2] + red[3]) * (1.f / HIDDEN);

    float lv = 0.f;
    for (int i = tid; i < HIDDEN; i += 256) {
        float d = xs[i] - mu;
        lv += d * d;
    }
    #pragma unroll
    for (int off = 32; off > 0; off >>= 1) lv += __shfl_down(lv, off, 64);
    if (lane == 0) red[4 + wid] = lv;
    __syncthreads();
    float var = (red[4] + red[5] + red[6] + red[7]) * (1.f / HIDDEN);
    float rstd = rsqrtf(var + EPS);

    for (int i = tid; i < HIDDEN; i += 256) {
        o[i] = (xs[i] - mu) * rstd * gamma[i] + beta[i];
    }
}

// ---------------------------------------------------------------------------
extern "C" void kernel_launch(void* const* d_in, const int* in_sizes, int n_in,
                              void* d_out, int out_size, void* d_ws, size_t ws_size,
                              hipStream_t stream)
{
    const float* X     = (const float*)d_in[0];
    const float* Wq    = (const float*)d_in[1];
    const float* bq    = (const float*)d_in[2];
    const float* Wk    = (const float*)d_in[3];
    const float* bk    = (const float*)d_in[4];
    const float* Wv    = (const float*)d_in[5];
    const float* bv    = (const float*)d_in[6];
    const float* Wo    = (const float*)d_in[7];
    const float* bo    = (const float*)d_in[8];
    const float* gamma = (const float*)d_in[9];
    const float* beta  = (const float*)d_in[10];
    float* out = (float*)d_out;

    const int B = 2, S = 2048;
    const int M = B * S;                       // 4096
    const size_t mat = (size_t)M * HIDDEN;     // 4M elems

    char* ws = (char*)d_ws;
    short* Xb  = (short*)(ws);                          // 8 MB
    short* Wqt = (short*)(ws + (8 << 20));              // 2 MB each
    short* Wkt = (short*)(ws + (10 << 20));
    short* Wvt = (short*)(ws + (12 << 20));
    short* Wot = (short*)(ws + (14 << 20));
    short* Qb  = (short*)(ws + (16 << 20));             // 8 MB
    short* Kb  = (short*)(ws + (24 << 20));             // 8 MB
    short* Vb  = (short*)(ws + (32 << 20));             // 8 MB
    short* Cx  = (short*)(ws + (40 << 20));             // 8 MB
    float* Pj  = (float*)(ws + (16 << 20));             // 16 MB, overlays Qb/Kb

    dim3 blk(256);

    cast_bf16_kernel<<<dim3((int)(mat / 4 + 255) / 256), blk, 0, stream>>>(X, Xb, (int)mat);

    dim3 tgrid(HIDDEN / 32, HIDDEN / 32);
    transpose_cast_kernel<<<tgrid, blk, 0, stream>>>(Wq, Wqt, HIDDEN, HIDDEN);
    transpose_cast_kernel<<<tgrid, blk, 0, stream>>>(Wk, Wkt, HIDDEN, HIDDEN);
    transpose_cast_kernel<<<tgrid, blk, 0, stream>>>(Wv, Wvt, HIDDEN, HIDDEN);
    transpose_cast_kernel<<<tgrid, blk, 0, stream>>>(Wo, Wot, HIDDEN, HIDDEN);

    dim3 ggrid(HIDDEN / 128, M / 128);         // (8, 32)
    gemm_bt_mfma<<<ggrid, blk, 0, stream>>>(Xb, Wqt, bq, Qb, M, HIDDEN, HIDDEN, 1);
    gemm_bt_mfma<<<ggrid, blk, 0, stream>>>(Xb, Wkt, bk, Kb, M, HIDDEN, HIDDEN, 1);
    gemm_bt_mfma<<<ggrid, blk, 0, stream>>>(Xb, Wvt, bv, Vb, M, HIDDEN, HIDDEN, 1);

    dim3 agrid(S / 64, HEADS, B);              // (32, 16, 2)
    attn_mfma_kernel<<<agrid, blk, 0, stream>>>(Qb, Kb, Vb, Cx, S);

    gemm_bt_mfma<<<ggrid, blk, 0, stream>>>(Cx, Wot, bo, Pj, M, HIDDEN, HIDDEN, 0);

    resln_kernel<<<M, blk, 0, stream>>>(Pj, X, gamma, beta, out);
}

// Round 3
// 266.788 us; speedup vs baseline: 15.4055x; 1.3730x over previous
//
#include <hip/hip_runtime.h>
#include <hip/hip_bf16.h>
#include <math.h>

#define HIDDEN 1024
#define HEADS 16
#define HEAD_DIM 64
#define EPS 1e-5f

typedef __attribute__((ext_vector_type(8))) short bf16x8;
typedef __attribute__((ext_vector_type(4))) float f32x4;

#if defined(__has_builtin)
#if __has_builtin(__builtin_amdgcn_exp2f)
#define EXP2(x) __builtin_amdgcn_exp2f(x)
#endif
#endif
#ifndef EXP2
#define EXP2(x) exp2f(x)
#endif

// 0.125 (1/sqrt(64)) * log2(e): folded into Wq so softmax is exp2(s)
#define QSCALE 0.18033688011112042f

__device__ __forceinline__ short f2bf(float f) {
    union { float f; unsigned u; } v; v.f = f;
    unsigned r = v.u + 0x7fffu + ((v.u >> 16) & 1u);   // RNE
    return (short)(r >> 16);
}

// ---------------------------------------------------------------------------
// fp32 -> bf16 cast, 4 elems/thread
// ---------------------------------------------------------------------------
__global__ __launch_bounds__(256) void cast_bf16_kernel(
    const float* __restrict__ in, short* __restrict__ out, int n)
{
    int i = (blockIdx.x * 256 + threadIdx.x) * 4;
    if (i >= n) return;
    float4 v = *(const float4*)(in + i);
    short o[4] = { f2bf(v.x), f2bf(v.y), f2bf(v.z), f2bf(v.w) };
    *(uint2*)(out + i) = *(uint2*)o;
}

// ---------------------------------------------------------------------------
// W[K,N] fp32 -> Wt[N,K] bf16 (32x32 tiles through LDS), with scale
// ---------------------------------------------------------------------------
__global__ __launch_bounds__(256) void transpose_cast_kernel(
    const float* __restrict__ W, short* __restrict__ Wt, int Kd, int Nd,
    float scale)
{
    __shared__ short tile[32][33];
    int n0 = blockIdx.x * 32;
    int k0 = blockIdx.y * 32;
    int tx = threadIdx.x & 31;
    int ty = threadIdx.x >> 5;  // 0..7
    #pragma unroll
    for (int i = 0; i < 32; i += 8)
        tile[ty + i][tx] = f2bf(W[(size_t)(k0 + ty + i) * Nd + n0 + tx] * scale);
    __syncthreads();
    #pragma unroll
    for (int i = 0; i < 32; i += 8)
        Wt[(size_t)(n0 + ty + i) * Kd + k0 + tx] = tile[tx][ty + i];
}

// ---------------------------------------------------------------------------
// b3 = concat(bq*qscale, bk, bv)
// ---------------------------------------------------------------------------
__global__ __launch_bounds__(256) void concat_bias_kernel(
    const float* __restrict__ bq, const float* __restrict__ bk,
    const float* __restrict__ bv, float* __restrict__ b3)
{
    int i = blockIdx.x * 256 + threadIdx.x;
    if (i >= 3072) return;
    float v = (i < 1024) ? bq[i] * QSCALE
            : (i < 2048) ? bk[i - 1024] : bv[i - 2048];
    b3[i] = v;
}

// ---------------------------------------------------------------------------
// C[M,N] = A[M,K] @ Bt[N,K]^T + bias[col].  Columns >= split_col go to C1
// (col index rebased), else C0.  128x128 tile, BK=32, 4 waves.
// ---------------------------------------------------------------------------
__global__ __launch_bounds__(256) void gemm_bt_mfma(
    const short* __restrict__ A, const short* __restrict__ Bt,
    const float* __restrict__ bias,
    void* __restrict__ C0, int ldc0,
    void* __restrict__ C1, int split_col, int ldc1,
    int M, int N, int K, int out_bf16)
{
    __shared__ short As[128][40];
    __shared__ short Bs[128][40];
    const int tid = threadIdx.x;
    const int wave = tid >> 6, lane = tid & 63;
    const int ln16 = lane & 15, quad = lane >> 4;
    const int wm = (wave >> 1) * 64, wn = (wave & 1) * 64;
    const int brow = blockIdx.y * 128, bcol = blockIdx.x * 128;

    f32x4 acc[4][4];
    #pragma unroll
    for (int mt = 0; mt < 4; ++mt)
        #pragma unroll
        for (int nt = 0; nt < 4; ++nt) acc[mt][nt] = (f32x4){0.f, 0.f, 0.f, 0.f};

    for (int k0 = 0; k0 < K; k0 += 32) {
        #pragma unroll
        for (int i = 0; i < 2; ++i) {
            int idx = tid + i * 256;       // 0..511
            int r = idx >> 2;              // 0..127
            int c0 = (idx & 3) * 8;
            *(uint4*)&As[r][c0] = *(const uint4*)(A + (size_t)(brow + r) * K + k0 + c0);
            *(uint4*)&Bs[r][c0] = *(const uint4*)(Bt + (size_t)(bcol + r) * K + k0 + c0);
        }
        __syncthreads();
        bf16x8 af[4], bf[4];
        #pragma unroll
        for (int mt = 0; mt < 4; ++mt)
            af[mt] = *(const bf16x8*)&As[wm + mt * 16 + ln16][quad * 8];
        #pragma unroll
        for (int nt = 0; nt < 4; ++nt)
            bf[nt] = *(const bf16x8*)&Bs[wn + nt * 16 + ln16][quad * 8];
        #pragma unroll
        for (int mt = 0; mt < 4; ++mt)
            #pragma unroll
            for (int nt = 0; nt < 4; ++nt)
                acc[mt][nt] = __builtin_amdgcn_mfma_f32_16x16x32_bf16(
                    af[mt], bf[nt], acc[mt][nt], 0, 0, 0);
        __syncthreads();
    }

    void* Cp = C0; int ld = ldc0; int coff = 0;
    if (bcol >= split_col) { Cp = C1; ld = ldc1; coff = split_col; }

    #pragma unroll
    for (int mt = 0; mt < 4; ++mt) {
        #pragma unroll
        for (int r = 0; r < 4; ++r) {
            int row = brow + wm + mt * 16 + quad * 4 + r;
            #pragma unroll
            for (int nt = 0; nt < 4; ++nt) {
                int col = bcol + wn + nt * 16 + ln16;
                float v = acc[mt][nt][r] + bias[col];
                if (out_bf16) ((short*)Cp)[(size_t)row * ld + (col - coff)] = f2bf(v);
                else          ((float*)Cp)[(size_t)row * ld + (col - coff)] = v;
            }
        }
    }
}

// ---------------------------------------------------------------------------
// Vb[4096][1024] bf16 -> VT[1024][4096] bf16, 64x64 tiles
// ---------------------------------------------------------------------------
__global__ __launch_bounds__(256) void vtranspose_kernel(
    const short* __restrict__ Vb, short* __restrict__ VT)
{
    __shared__ short t[64][72];
    const int c0 = blockIdx.x * 64;    // feature block
    const int r0 = blockIdx.y * 64;    // token block
    const int tid = threadIdx.x;
    #pragma unroll
    for (int i = 0; i < 2; ++i) {
        int idx = tid + i * 256;
        int r = idx >> 3, cc = (idx & 7) * 8;
        *(uint4*)&t[r][cc] = *(const uint4*)(Vb + (size_t)(r0 + r) * 1024 + c0 + cc);
    }
    __syncthreads();
    #pragma unroll
    for (int i = 0; i < 2; ++i) {
        int idx = tid + i * 256;
        int c = idx >> 3, rr = (idx & 7) * 8;
        short tmp[8];
        #pragma unroll
        for (int j = 0; j < 8; ++j) tmp[j] = t[rr + j][c];
        *(uint4*)(VT + (size_t)(c0 + c) * 4096 + r0 + rr) = *(uint4*)tmp;
    }
}

// ---------------------------------------------------------------------------
// MFMA flash attention, fixed-max softmax (p = exp2(s), scale pre-folded
// into Wq).  QKb[4096][2048]: Q cols 0..1023, K cols 1024..2047.
// VT[1024][4096] = V^T.  Block = (qt, h, b); 4 waves; wave owns 16 q-rows.
// S^T trick: mfma(A=Kfrag, B=Qfrag) puts 4 consecutive-k P values per lane
// -> b64 P writes, b128 P reads.  Row-sum l via ones-fragment MFMA.
// ---------------------------------------------------------------------------
__global__ __launch_bounds__(256) void attn_mfma_kernel(
    const short* __restrict__ QKb, const short* __restrict__ VT,
    short* __restrict__ Ctx)
{
    const int S = 2048;
    const int qt = blockIdx.x, h = blockIdx.y, b = blockIdx.z;
    const int tid = threadIdx.x;
    const int wave = tid >> 6, lane = tid & 63;
    const int ln16 = lane & 15, quad = lane >> 4;

    __shared__ short Ks[64][72];   // [k-token][d]
    __shared__ short Vs[64][72];   // [d][k-token]  (from VT)
    __shared__ short Ps[64][72];   // [q][k-token]  (per-wave 16-row slices)

    // Q fragment (B-operand) straight from global, kept in registers
    const size_t qrow = (size_t)(b * S + qt * 64 + wave * 16 + ln16);
    bf16x8 qfrag[2];
    qfrag[0] = *(const bf16x8*)(QKb + qrow * 2048 + h * 64 + quad * 8);
    qfrag[1] = *(const bf16x8*)(QKb + qrow * 2048 + h * 64 + 32 + quad * 8);

    bf16x8 ones;
    #pragma unroll
    for (int j = 0; j < 8; ++j) ones[j] = (short)0x3F80;  // bf16 1.0

    f32x4 ofrag[4], lacc = (f32x4){0.f, 0.f, 0.f, 0.f};
    #pragma unroll
    for (int nt = 0; nt < 4; ++nt) ofrag[nt] = (f32x4){0.f, 0.f, 0.f, 0.f};

    for (int kt = 0; kt < S / 64; ++kt) {
        __syncthreads();   // all waves done with Ks/Vs of previous tile
        #pragma unroll
        for (int i = 0; i < 2; ++i) {
            int idx = tid + i * 256;
            int r = idx >> 3, c0 = (idx & 7) * 8;
            *(uint4*)&Ks[r][c0] = *(const uint4*)(
                QKb + (size_t)(b * S + kt * 64 + r) * 2048 + 1024 + h * 64 + c0);
            *(uint4*)&Vs[r][c0] = *(const uint4*)(
                VT + (size_t)(h * 64 + r) * 4096 + b * S + kt * 64 + c0);
        }
        __syncthreads();

        // S^T = K Q^T : row = k-token (quad*4+r), col = q (ln16)
        f32x4 sf[4];
        #pragma unroll
        for (int nt = 0; nt < 4; ++nt) {
            f32x4 a = (f32x4){0.f, 0.f, 0.f, 0.f};
            a = __builtin_amdgcn_mfma_f32_16x16x32_bf16(
                *(const bf16x8*)&Ks[nt * 16 + ln16][quad * 8], qfrag[0], a, 0, 0, 0);
            a = __builtin_amdgcn_mfma_f32_16x16x32_bf16(
                *(const bf16x8*)&Ks[nt * 16 + ln16][32 + quad * 8], qfrag[1], a, 0, 0, 0);
            sf[nt] = a;
        }

        // p = exp2(s); pack 4 consecutive-k values -> one b64 write
        #pragma unroll
        for (int nt = 0; nt < 4; ++nt) {
            float p0 = EXP2(sf[nt][0]), p1 = EXP2(sf[nt][1]);
            float p2 = EXP2(sf[nt][2]), p3 = EXP2(sf[nt][3]);
            union { __hip_bfloat162 h2; unsigned u; } c01, c23;
            c01.h2 = __float22bfloat162_rn(make_float2(p0, p1));
            c23.h2 = __float22bfloat162_rn(make_float2(p2, p3));
            uint2 w; w.x = c01.u; w.y = c23.u;
            *(uint2*)&Ps[wave * 16 + ln16][nt * 16 + quad * 4] = w;
        }

        // O += P V  (A = P rows of this wave, B = V^T rows)
        bf16x8 pf0 = *(const bf16x8*)&Ps[wave * 16 + ln16][quad * 8];
        bf16x8 pf1 = *(const bf16x8*)&Ps[wave * 16 + ln16][32 + quad * 8];
        lacc = __builtin_amdgcn_mfma_f32_16x16x32_bf16(pf0, ones, lacc, 0, 0, 0);
        lacc = __builtin_amdgcn_mfma_f32_16x16x32_bf16(pf1, ones, lacc, 0, 0, 0);
        #pragma unroll
        for (int nt = 0; nt < 4; ++nt) {
            f32x4 a = ofrag[nt];
            a = __builtin_amdgcn_mfma_f32_16x16x32_bf16(
                pf0, *(const bf16x8*)&Vs[nt * 16 + ln16][quad * 8], a, 0, 0, 0);
            a = __builtin_amdgcn_mfma_f32_16x16x32_bf16(
                pf1, *(const bf16x8*)&Vs[nt * 16 + ln16][32 + quad * 8], a, 0, 0, 0);
            ofrag[nt] = a;
        }
    }

    #pragma unroll
    for (int r = 0; r < 4; ++r) {
        float inv = 1.f / lacc[r];
        int row = b * S + qt * 64 + wave * 16 + quad * 4 + r;
        #pragma unroll
        for (int nt = 0; nt < 4; ++nt)
            Ctx[(size_t)row * 1024 + h * 64 + nt * 16 + ln16] =
                f2bf(ofrag[nt][r] * inv);
    }
}

// ---------------------------------------------------------------------------
// out = LayerNorm(proj + residual) * gamma + beta, one block per row (fp32)
// ---------------------------------------------------------------------------
__global__ __launch_bounds__(256) void resln_kernel(
    const float* __restrict__ proj, const float* __restrict__ resid,
    const float* __restrict__ gamma, const float* __restrict__ beta,
    float* __restrict__ out)
{
    const int rowi = blockIdx.x;
    const float* p = proj + (size_t)rowi * HIDDEN;
    const float* r = resid + (size_t)rowi * HIDDEN;
    float* o = out + (size_t)rowi * HIDDEN;
    const int tid = threadIdx.x;

    __shared__ float xs[HIDDEN];
    __shared__ float red[8];

    float local = 0.f;
    for (int i = tid; i < HIDDEN; i += 256) {
        float x = p[i] + r[i];
        xs[i] = x;
        local += x;
    }
    const int wid = tid >> 6, lane = tid & 63;
    #pragma unroll
    for (int off = 32; off > 0; off >>= 1) local += __shfl_down(local, off, 64);
    if (lane == 0) red[wid] = local;
    __syncthreads();
    float mu = (red[0] + red[1] + red[2] + red[3]) * (1.f / HIDDEN);

    float lv = 0.f;
    for (int i = tid; i < HIDDEN; i += 256) {
        float d = xs[i] - mu;
        lv += d * d;
    }
    #pragma unroll
    for (int off = 32; off > 0; off >>= 1) lv += __shfl_down(lv, off, 64);
    if (lane == 0) red[4 + wid] = lv;
    __syncthreads();
    float var = (red[4] + red[5] + red[6] + red[7]) * (1.f / HIDDEN);
    float rstd = rsqrtf(var + EPS);

    for (int i = tid; i < HIDDEN; i += 256) {
        o[i] = (xs[i] - mu) * rstd * gamma[i] + beta[i];
    }
}

// ---------------------------------------------------------------------------
extern "C" void kernel_launch(void* const* d_in, const int* in_sizes, int n_in,
                              void* d_out, int out_size, void* d_ws, size_t ws_size,
                              hipStream_t stream)
{
    const float* X     = (const float*)d_in[0];
    const float* Wq    = (const float*)d_in[1];
    const float* bq    = (const float*)d_in[2];
    const float* Wk    = (const float*)d_in[3];
    const float* bk    = (const float*)d_in[4];
    const float* Wv    = (const float*)d_in[5];
    const float* bv    = (const float*)d_in[6];
    const float* Wo    = (const float*)d_in[7];
    const float* bo    = (const float*)d_in[8];
    const float* gamma = (const float*)d_in[9];
    const float* beta  = (const float*)d_in[10];
    float* out = (float*)d_out;

    const int B = 2, S = 2048;
    const int M = B * S;                       // 4096
    const size_t mat = (size_t)M * HIDDEN;     // 4M elems

    // workspace map (peak 41 MB):
    //   [0,8)    Xb  (dead after QKV gemm)  -> VT overlays
    //   [8,10)   Wot
    //   [10,16)  Wt3 (3072x1024 bf16)
    //   [16,~)   b3  (3072 fp32)
    //   [17,33)  QKb (4096x2048 bf16; dead after attn) -> Pj (fp32) overlays
    //   [33,41)  Vb  (4096x1024 bf16; dead after vtrans) -> Ctx overlays
    char* ws = (char*)d_ws;
    short* Xb  = (short*)(ws);
    short* VT  = (short*)(ws);
    short* Wot = (short*)(ws + (8ull << 20));
    short* Wt3 = (short*)(ws + (10ull << 20));
    float* b3  = (float*)(ws + (16ull << 20));
    short* QKb = (short*)(ws + (17ull << 20));
    float* Pj  = (float*)(ws + (17ull << 20));
    short* Vb  = (short*)(ws + (33ull << 20));
    short* Ctx = (short*)(ws + (33ull << 20));

    dim3 blk(256);

    cast_bf16_kernel<<<dim3((int)(mat / 4 + 255) / 256), blk, 0, stream>>>(X, Xb, (int)mat);

    dim3 tgrid(HIDDEN / 32, HIDDEN / 32);
    transpose_cast_kernel<<<tgrid, blk, 0, stream>>>(Wq, Wt3,                
                                                     HIDDEN, HIDDEN, QSCALE);
    transpose_cast_kernel<<<tgrid, blk, 0, stream>>>(Wk, Wt3 + 1024 * 1024,
                                                     HIDDEN, HIDDEN, 1.0f);
    transpose_cast_kernel<<<tgrid, blk, 0, stream>>>(Wv, Wt3 + 2048 * 1024,
                                                     HIDDEN, HIDDEN, 1.0f);
    transpose_cast_kernel<<<tgrid, blk, 0, stream>>>(Wo, Wot,
                                                     HIDDEN, HIDDEN, 1.0f);
    concat_bias_kernel<<<12, blk, 0, stream>>>(bq, bk, bv, b3);

    // fused QKV projection: N=3072, V columns routed to Vb
    dim3 qkvgrid(3072 / 128, M / 128);         // (24, 32) = 768 blocks
    gemm_bt_mfma<<<qkvgrid, blk, 0, stream>>>(Xb, Wt3, b3,
                                              QKb, 2048, Vb, 2048, 1024,
                                              M, 3072, HIDDEN, 1);

    vtranspose_kernel<<<dim3(16, 64), blk, 0, stream>>>(Vb, VT);

    dim3 agrid(S / 64, HEADS, B);              // (32, 16, 2)
    attn_mfma_kernel<<<agrid, blk, 0, stream>>>(QKb, VT, Ctx);

    dim3 ogrid(HIDDEN / 128, M / 128);         // (8, 32)
    gemm_bt_mfma<<<ogrid, blk, 0, stream>>>(Ctx, Wot, bo,
                                            Pj, 1024, nullptr, 1 << 30, 0,
                                            M, HIDDEN, HIDDEN, 0);

    resln_kernel<<<M, blk, 0, stream>>>(Pj, X, gamma, beta, out);
}

// Round 4
// 243.588 us; speedup vs baseline: 16.8727x; 1.0952x over previous
//
#include <hip/hip_runtime.h>
#include <hip/hip_bf16.h>
#include <math.h>

#define HIDDEN 1024
#define HEADS 16
#define HEAD_DIM 64
#define EPS 1e-5f

typedef __attribute__((ext_vector_type(8))) short bf16x8;
typedef __attribute__((ext_vector_type(4))) float f32x4;

#if defined(__has_builtin)
#if __has_builtin(__builtin_amdgcn_exp2f)
#define EXP2(x) __builtin_amdgcn_exp2f(x)
#endif
#endif
#ifndef EXP2
#define EXP2(x) exp2f(x)
#endif

// 0.125 (1/sqrt(64)) * log2(e): folded into Wq/bq so softmax is exp2(s)
#define QSCALE 0.18033688011112042f

__device__ __forceinline__ short f2bf(float f) {
    union { float f; unsigned u; } v; v.f = f;
    unsigned r = v.u + 0x7fffu + ((v.u >> 16) & 1u);   // RNE
    return (short)(r >> 16);
}

// async global->LDS DMA, 16 B per lane; dest = ldsbase + lane*16 (wave-uniform base)
__device__ __forceinline__ void gl_lds16(const void* g, void* l) {
    __builtin_amdgcn_global_load_lds(
        (const __attribute__((address_space(1))) void*)g,
        (__attribute__((address_space(3))) void*)l, 16, 0, 0);
}

// ---------------------------------------------------------------------------
// fp32 -> bf16 cast, 4 elems/thread
// ---------------------------------------------------------------------------
__global__ __launch_bounds__(256) void cast_bf16_kernel(
    const float* __restrict__ in, short* __restrict__ out, int n)
{
    int i = (blockIdx.x * 256 + threadIdx.x) * 4;
    if (i >= n) return;
    float4 v = *(const float4*)(in + i);
    short o[4] = { f2bf(v.x), f2bf(v.y), f2bf(v.z), f2bf(v.w) };
    *(uint2*)(out + i) = *(uint2*)o;
}

// ---------------------------------------------------------------------------
// All 4 weights: W[K,N] fp32 -> Wt[N,K] bf16 (32x32 tiles), z picks weight
// ---------------------------------------------------------------------------
__global__ __launch_bounds__(256) void wtrans_kernel(
    const float* __restrict__ Wq, const float* __restrict__ Wk,
    const float* __restrict__ Wv, const float* __restrict__ Wo,
    short* __restrict__ Wt3, short* __restrict__ Wot)
{
    const int wsel = blockIdx.z;
    const float* W = (wsel == 0) ? Wq : (wsel == 1) ? Wk : (wsel == 2) ? Wv : Wo;
    short* dst = (wsel < 3) ? (Wt3 + (size_t)wsel * 1024 * 1024) : Wot;
    const float scale = (wsel == 0) ? QSCALE : 1.0f;

    __shared__ short tile[32][33];
    int n0 = blockIdx.x * 32;
    int k0 = blockIdx.y * 32;
    int tx = threadIdx.x & 31;
    int ty = threadIdx.x >> 5;  // 0..7
    #pragma unroll
    for (int i = 0; i < 32; i += 8)
        tile[ty + i][tx] = f2bf(W[(size_t)(k0 + ty + i) * 1024 + n0 + tx] * scale);
    __syncthreads();
    #pragma unroll
    for (int i = 0; i < 32; i += 8)
        dst[(size_t)(n0 + ty + i) * 1024 + k0 + tx] = tile[tx][ty + i];
}

// ---------------------------------------------------------------------------
// b3 = concat(bq*qscale, bk, bv)
// ---------------------------------------------------------------------------
__global__ __launch_bounds__(256) void concat_bias_kernel(
    const float* __restrict__ bq, const float* __restrict__ bk,
    const float* __restrict__ bv, float* __restrict__ b3)
{
    int i = blockIdx.x * 256 + threadIdx.x;
    if (i >= 3072) return;
    float v = (i < 1024) ? bq[i] * QSCALE
            : (i < 2048) ? bk[i - 1024] : bv[i - 2048];
    b3[i] = v;
}

// ---------------------------------------------------------------------------
// C[M,N] = A[M,K] @ Bt[N,K]^T + bias[col] (+ resid fp32 if given).
// 128x128 tile, BK=32, 4 waves. Staging via global_load_lds (16B DMA),
// XOR-swizzled source columns so LDS is unpadded yet fragment reads are
// bank-balanced. Columns >= split_col go to C1 (rebased), else C0.
// ---------------------------------------------------------------------------
__global__ __launch_bounds__(256) void gemm_bt_mfma(
    const short* __restrict__ A, const short* __restrict__ Bt,
    const float* __restrict__ bias,
    void* __restrict__ C0, int ldc0,
    void* __restrict__ C1, int split_col, int ldc1,
    const float* __restrict__ resid,
    int M, int N, int K, int out_bf16)
{
    __shared__ short As[128 * 32];
    __shared__ short Bs[128 * 32];
    const int tid = threadIdx.x;
    const int wave = tid >> 6, lane = tid & 63;
    const int ln16 = lane & 15, quad = lane >> 4;
    const int wm = (wave >> 1) * 64, wn = (wave & 1) * 64;
    const int brow = blockIdx.y * 128, bcol = blockIdx.x * 128;

    const int sr  = lane >> 2;   // 0..15 row within 16-row chunk
    const int scb = lane & 3;    // lds col-block (8 shorts)

    f32x4 acc[4][4];
    #pragma unroll
    for (int mt = 0; mt < 4; ++mt)
        #pragma unroll
        for (int nt = 0; nt < 4; ++nt) acc[mt][nt] = (f32x4){0.f, 0.f, 0.f, 0.f};

    for (int k0 = 0; k0 < K; k0 += 32) {
        __syncthreads();
        #pragma unroll
        for (int i = 0; i < 2; ++i) {
            int rb = i * 64 + wave * 16;          // chunk base row (wave-uniform)
            int r  = rb + sr;
            int csrc = (scb ^ ((r >> 1) & 3)) * 8;
            gl_lds16(A  + (size_t)(brow + r) * K + k0 + csrc, &As[rb * 32]);
            gl_lds16(Bt + (size_t)(bcol + r) * K + k0 + csrc, &Bs[rb * 32]);
        }
        __syncthreads();

        bf16x8 af[4], bf[4];
        #pragma unroll
        for (int mt = 0; mt < 4; ++mt) {
            int r = wm + mt * 16 + ln16;
            af[mt] = *(const bf16x8*)&As[r * 32 + ((quad ^ ((r >> 1) & 3)) * 8)];
        }
        #pragma unroll
        for (int nt = 0; nt < 4; ++nt) {
            int r = wn + nt * 16 + ln16;
            bf[nt] = *(const bf16x8*)&Bs[r * 32 + ((quad ^ ((r >> 1) & 3)) * 8)];
        }
        #pragma unroll
        for (int mt = 0; mt < 4; ++mt)
            #pragma unroll
            for (int nt = 0; nt < 4; ++nt)
                acc[mt][nt] = __builtin_amdgcn_mfma_f32_16x16x32_bf16(
                    af[mt], bf[nt], acc[mt][nt], 0, 0, 0);
    }

    void* Cp = C0; int ld = ldc0; int coff = 0;
    if (bcol >= split_col) { Cp = C1; ld = ldc1; coff = split_col; }

    #pragma unroll
    for (int mt = 0; mt < 4; ++mt) {
        #pragma unroll
        for (int r = 0; r < 4; ++r) {
            int row = brow + wm + mt * 16 + quad * 4 + r;
            #pragma unroll
            for (int nt = 0; nt < 4; ++nt) {
                int col = bcol + wn + nt * 16 + ln16;
                float v = acc[mt][nt][r] + bias[col];
                if (resid) v += resid[(size_t)row * N + col];
                if (out_bf16) ((short*)Cp)[(size_t)row * ld + (col - coff)] = f2bf(v);
                else          ((float*)Cp)[(size_t)row * ld + (col - coff)] = v;
            }
        }
    }
}

// ---------------------------------------------------------------------------
// Vb[4096][1024] bf16 -> VT[1024][4096] bf16, 64x64 tiles
// ---------------------------------------------------------------------------
__global__ __launch_bounds__(256) void vtranspose_kernel(
    const short* __restrict__ Vb, short* __restrict__ VT)
{
    __shared__ short t[64][72];
    const int c0 = blockIdx.x * 64;    // feature block
    const int r0 = blockIdx.y * 64;    // token block
    const int tid = threadIdx.x;
    #pragma unroll
    for (int i = 0; i < 2; ++i) {
        int idx = tid + i * 256;
        int r = idx >> 3, cc = (idx & 7) * 8;
        *(uint4*)&t[r][cc] = *(const uint4*)(Vb + (size_t)(r0 + r) * 1024 + c0 + cc);
    }
    __syncthreads();
    #pragma unroll
    for (int i = 0; i < 2; ++i) {
        int idx = tid + i * 256;
        int c = idx >> 3, rr = (idx & 7) * 8;
        short tmp[8];
        #pragma unroll
        for (int j = 0; j < 8; ++j) tmp[j] = t[rr + j][c];
        *(uint4*)(VT + (size_t)(c0 + c) * 4096 + r0 + rr) = *(uint4*)tmp;
    }
}

// ---------------------------------------------------------------------------
// MFMA flash attention, fixed-max softmax (p = exp2(s); scale pre-folded).
// QKb[4096][2048]: Q cols 0..1023, K cols 1024..2047.  VT[1024][4096] = V^T.
// Block = (h, qt, b): 128 q-rows; 4 waves, wave owns 32 q-rows (2 groups of
// 16).  K/V tiles DMA-staged via global_load_lds with XOR-swizzled source
// columns.  S^T trick (A=K, B=Q) -> b64 P writes / b128 P reads.  Row-sum l
// via ones-fragment MFMA.  Grid is h-major so each XCD's L2 holds 2 heads'
// K/V stream.
// ---------------------------------------------------------------------------
__global__ __launch_bounds__(256) void attn_mfma_kernel(
    const short* __restrict__ QKb, const short* __restrict__ VT,
    short* __restrict__ Ctx)
{
    const int S = 2048;
    const int h = blockIdx.x, qt = blockIdx.y, b = blockIdx.z;
    const int tid = threadIdx.x;
    const int wave = tid >> 6, lane = tid & 63;
    const int ln16 = lane & 15, quad = lane >> 4;

    __shared__ short Ks[64 * 64];    // [k-token][d], swizzled
    __shared__ short Vs[64 * 64];    // [d][k-token], swizzled
    __shared__ short Ps[128 * 72];   // [q][k-token], padded pitch (not DMA'd)

    const int q0 = qt * 128 + wave * 32;

    // Q fragments (B-operand), straight from global, live in registers
    bf16x8 qfrag[2][2];
    #pragma unroll
    for (int qg = 0; qg < 2; ++qg)
        #pragma unroll
        for (int kb = 0; kb < 2; ++kb)
            qfrag[qg][kb] = *(const bf16x8*)(QKb +
                (size_t)(b * S + q0 + qg * 16 + ln16) * 2048 + h * 64 + kb * 32 + quad * 8);

    bf16x8 ones;
    #pragma unroll
    for (int j = 0; j < 8; ++j) ones[j] = (short)0x3F80;  // bf16 1.0

    f32x4 of[2][4], lacc[2];
    #pragma unroll
    for (int qg = 0; qg < 2; ++qg) {
        lacc[qg] = (f32x4){0.f, 0.f, 0.f, 0.f};
        #pragma unroll
        for (int nt = 0; nt < 4; ++nt) of[qg][nt] = (f32x4){0.f, 0.f, 0.f, 0.f};
    }

    const int sr  = lane >> 3;   // 0..7 row within 8-row chunk
    const int scb = lane & 7;    // lds col-block

    for (int kt = 0; kt < S / 64; ++kt) {
        __syncthreads();   // prev tile's K/V reads done
        #pragma unroll
        for (int i = 0; i < 2; ++i) {
            int ci = wave * 2 + i;            // chunk 0..7 (8 rows each)
            int r  = ci * 8 + sr;             // 0..63
            int csrc = ((scb ^ (r & 7))) * 8;
            gl_lds16(QKb + (size_t)(b * S + kt * 64 + r) * 2048 + 1024 + h * 64 + csrc,
                     &Ks[ci * 512]);
            gl_lds16(VT + (size_t)(h * 64 + r) * 4096 + b * S + kt * 64 + csrc,
                     &Vs[ci * 512]);
        }
        __syncthreads();

        // S^T = K Q^T ; exp2 ; pack 4 consecutive-k bf16 -> b64 write
        #pragma unroll
        for (int nt = 0; nt < 4; ++nt) {
            bf16x8 kf[2];
            #pragma unroll
            for (int kb = 0; kb < 2; ++kb) {
                int r = nt * 16 + ln16;
                int cb = (kb * 4 + quad) ^ (r & 7);
                kf[kb] = *(const bf16x8*)&Ks[r * 64 + cb * 8];
            }
            #pragma unroll
            for (int qg = 0; qg < 2; ++qg) {
                f32x4 a = (f32x4){0.f, 0.f, 0.f, 0.f};
                a = __builtin_amdgcn_mfma_f32_16x16x32_bf16(kf[0], qfrag[qg][0], a, 0, 0, 0);
                a = __builtin_amdgcn_mfma_f32_16x16x32_bf16(kf[1], qfrag[qg][1], a, 0, 0, 0);
                float p0 = EXP2(a[0]), p1 = EXP2(a[1]);
                float p2 = EXP2(a[2]), p3 = EXP2(a[3]);
                union { __hip_bfloat162 h2; unsigned u; } c01, c23;
                c01.h2 = __float22bfloat162_rn(make_float2(p0, p1));
                c23.h2 = __float22bfloat162_rn(make_float2(p2, p3));
                uint2 w; w.x = c01.u; w.y = c23.u;
                *(uint2*)&Ps[(wave * 32 + qg * 16 + ln16) * 72 + nt * 16 + quad * 4] = w;
            }
        }

        // P fragments (per-wave private region: no barrier needed)
        bf16x8 pf[2][2];
        #pragma unroll
        for (int qg = 0; qg < 2; ++qg)
            #pragma unroll
            for (int kb = 0; kb < 2; ++kb)
                pf[qg][kb] = *(const bf16x8*)
                    &Ps[(wave * 32 + qg * 16 + ln16) * 72 + kb * 32 + quad * 8];

        #pragma unroll
        for (int qg = 0; qg < 2; ++qg) {
            lacc[qg] = __builtin_amdgcn_mfma_f32_16x16x32_bf16(pf[qg][0], ones, lacc[qg], 0, 0, 0);
            lacc[qg] = __builtin_amdgcn_mfma_f32_16x16x32_bf16(pf[qg][1], ones, lacc[qg], 0, 0, 0);
        }
        #pragma unroll
        for (int nt = 0; nt < 4; ++nt) {
            bf16x8 vf[2];
            #pragma unroll
            for (int kb = 0; kb < 2; ++kb) {
                int r = nt * 16 + ln16;
                int cb = (kb * 4 + quad) ^ (r & 7);
                vf[kb] = *(const bf16x8*)&Vs[r * 64 + cb * 8];
            }
            #pragma unroll
            for (int qg = 0; qg < 2; ++qg) {
                of[qg][nt] = __builtin_amdgcn_mfma_f32_16x16x32_bf16(pf[qg][0], vf[0], of[qg][nt], 0, 0, 0);
                of[qg][nt] = __builtin_amdgcn_mfma_f32_16x16x32_bf16(pf[qg][1], vf[1], of[qg][nt], 0, 0, 0);
            }
        }
    }

    #pragma unroll
    for (int qg = 0; qg < 2; ++qg) {
        #pragma unroll
        for (int r = 0; r < 4; ++r) {
            float inv = 1.f / lacc[qg][r];
            int row = b * S + qt * 128 + wave * 32 + qg * 16 + quad * 4 + r;
            #pragma unroll
            for (int nt = 0; nt < 4; ++nt)
                Ctx[(size_t)row * 1024 + h * 64 + nt * 16 + ln16] =
                    f2bf(of[qg][nt][r] * inv);
        }
    }
}

// ---------------------------------------------------------------------------
// out = LayerNorm(x) * gamma + beta (residual already folded into x).
// One block per row; exactly one float4 per thread.
// ---------------------------------------------------------------------------
__global__ __launch_bounds__(256) void resln_kernel(
    const float* __restrict__ xin, const float* __restrict__ gamma,
    const float* __restrict__ beta, float* __restrict__ out)
{
    const int row = blockIdx.x;
    const int tid = threadIdx.x;
    const int wid = tid >> 6, lane = tid & 63;
    __shared__ float red[8];

    float4 x = *(const float4*)(xin + (size_t)row * HIDDEN + tid * 4);
    float s = x.x + x.y + x.z + x.w;
    #pragma unroll
    for (int off = 32; off > 0; off >>= 1) s += __shfl_xor(s, off, 64);
    if (lane == 0) red[wid] = s;
    __syncthreads();
    float mu = (red[0] + red[1] + red[2] + red[3]) * (1.f / HIDDEN);

    float dx = x.x - mu, dy = x.y - mu, dz = x.z - mu, dw = x.w - mu;
    float v = dx * dx + dy * dy + dz * dz + dw * dw;
    #pragma unroll
    for (int off = 32; off > 0; off >>= 1) v += __shfl_xor(v, off, 64);
    if (lane == 0) red[4 + wid] = v;
    __syncthreads();
    float var = (red[4] + red[5] + red[6] + red[7]) * (1.f / HIDDEN);
    float rstd = rsqrtf(var + EPS);

    float4 g = *(const float4*)(gamma + tid * 4);
    float4 bt = *(const float4*)(beta + tid * 4);
    float4 o;
    o.x = dx * rstd * g.x + bt.x;
    o.y = dy * rstd * g.y + bt.y;
    o.z = dz * rstd * g.z + bt.z;
    o.w = dw * rstd * g.w + bt.w;
    *(float4*)(out + (size_t)row * HIDDEN + tid * 4) = o;
}

// ---------------------------------------------------------------------------
extern "C" void kernel_launch(void* const* d_in, const int* in_sizes, int n_in,
                              void* d_out, int out_size, void* d_ws, size_t ws_size,
                              hipStream_t stream)
{
    const float* X     = (const float*)d_in[0];
    const float* Wq    = (const float*)d_in[1];
    const float* bq    = (const float*)d_in[2];
    const float* Wk    = (const float*)d_in[3];
    const float* bk    = (const float*)d_in[4];
    const float* Wv    = (const float*)d_in[5];
    const float* bv    = (const float*)d_in[6];
    const float* Wo    = (const float*)d_in[7];
    const float* bo    = (const float*)d_in[8];
    const float* gamma = (const float*)d_in[9];
    const float* beta  = (const float*)d_in[10];
    float* out = (float*)d_out;

    const int B = 2, S = 2048;
    const int M = B * S;                       // 4096
    const size_t mat = (size_t)M * HIDDEN;     // 4M elems

    // workspace map (peak 41 MB):
    //   [0,8)    Xb (dead after QKV gemm) -> VT overlays
    //   [8,10)   Wot
    //   [10,16)  Wt3 (3072x1024 bf16)
    //   [16,17)  b3
    //   [17,33)  QKb (dead after attn) -> Pj (fp32) overlays
    //   [33,41)  Vb (dead after vtrans) -> Ctx overlays
    char* ws = (char*)d_ws;
    short* Xb  = (short*)(ws);
    short* VT  = (short*)(ws);
    short* Wot = (short*)(ws + (8ull << 20));
    short* Wt3 = (short*)(ws + (10ull << 20));
    float* b3  = (float*)(ws + (16ull << 20));
    short* QKb = (short*)(ws + (17ull << 20));
    float* Pj  = (float*)(ws + (17ull << 20));
    short* Vb  = (short*)(ws + (33ull << 20));
    short* Ctx = (short*)(ws + (33ull << 20));

    dim3 blk(256);

    cast_bf16_kernel<<<dim3((int)(mat / 4 / 256)), blk, 0, stream>>>(X, Xb, (int)mat);
    wtrans_kernel<<<dim3(32, 32, 4), blk, 0, stream>>>(Wq, Wk, Wv, Wo, Wt3, Wot);
    concat_bias_kernel<<<12, blk, 0, stream>>>(bq, bk, bv, b3);

    // fused QKV projection: N=3072, V columns routed to Vb
    dim3 qkvgrid(3072 / 128, M / 128);         // (24, 32) = 768 blocks
    gemm_bt_mfma<<<qkvgrid, blk, 0, stream>>>(Xb, Wt3, b3,
                                              QKb, 2048, Vb, 2048, 1024,
                                              nullptr, M, 3072, HIDDEN, 1);

    vtranspose_kernel<<<dim3(16, 64), blk, 0, stream>>>(Vb, VT);

    dim3 agrid(HEADS, S / 128, B);             // (16, 16, 2) = 512 blocks
    attn_mfma_kernel<<<agrid, blk, 0, stream>>>(QKb, VT, Ctx);

    // output projection + bias + residual (fp32 out)
    dim3 ogrid(HIDDEN / 128, M / 128);         // (8, 32)
    gemm_bt_mfma<<<ogrid, blk, 0, stream>>>(Ctx, Wot, bo,
                                            Pj, 1024, nullptr, 1 << 30, 0,
                                            X, M, HIDDEN, HIDDEN, 0);

    resln_kernel<<<M, blk, 0, stream>>>(Pj, gamma, beta, out);
}